// Round 1
// 1022.909 us; speedup vs baseline: 1.0397x; 1.0397x over previous
//
#include <hip/hip_runtime.h>
#include <hip/hip_bf16.h>
#include <math.h>

typedef __hip_bfloat16 bf16;
typedef __attribute__((ext_vector_type(8))) short bf16x8;
typedef __attribute__((ext_vector_type(4))) float f32x4;

#define GPTR(p) ((__attribute__((address_space(1))) void*)(void*)(p))
#define LPTR(p) ((__attribute__((address_space(3))) void*)(void*)(p))

static constexpr int kB = 4, kL = 2048, kD = 1024, kV = 32000;
static constexpr int kM = kB * kL;                 // 8192
static constexpr int kNC = 16, kCH = kL / kNC;     // 16 chunks of 128

// ---------------- embedding gather ----------------
__global__ void k_embed(const int* __restrict__ tok, const float* __restrict__ emb,
                        float* __restrict__ h) {
  int row = blockIdx.x;
  int t = tok[row];
  const float4* s = (const float4*)(emb + (size_t)t * kD);
  float4* d = (float4*)(h + (size_t)row * kD);
  d[threadIdx.x] = s[threadIdx.x];
}

// ---------------- sincos tables ----------------
__global__ void k_sincos(const float* __restrict__ ph, float* __restrict__ c,
                         float* __restrict__ s, int n) {
  int i = blockIdx.x * 256 + threadIdx.x;
  if (i < n) {
    float sv, cv;
    sincosf(ph[i], &sv, &cv);
    c[i] = cv;
    s[i] = sv;
  }
}

// ---------------- transpose + f32 -> bf16 : in[R][C] -> out[C][R] ----------------
// 64x64 tile, 256 threads. Loads float4 (256B segments along C), stores bf16x8
// (128B segments along R). Replaces scalar-store 32x32 version (G13).
__global__ void k_tcvt64(const float* __restrict__ in, bf16* __restrict__ out,
                         int R, int C) {
  __shared__ bf16 tile[64][66];  // stride 66 elems = 132B: rotates banks, word-aligned rows
  int c0 = blockIdx.x * 64, r0 = blockIdx.y * 64;
  int tid = threadIdx.x;  // 256
  int cq = tid & 15;      // col-quad: cols cq*4 .. cq*4+3
  int rr = tid >> 4;      // 0..15
#pragma unroll
  for (int i = 0; i < 4; i++) {
    int r = rr + i * 16;
    float4 v = *(const float4*)(in + (size_t)(r0 + r) * C + c0 + cq * 4);
    tile[r][cq * 4 + 0] = __float2bfloat16(v.x);
    tile[r][cq * 4 + 1] = __float2bfloat16(v.y);
    tile[r][cq * 4 + 2] = __float2bfloat16(v.z);
    tile[r][cq * 4 + 3] = __float2bfloat16(v.w);
  }
  __syncthreads();
  int rb = tid & 7;   // row-octet: rows rb*8 .. rb*8+7
  int cc = tid >> 3;  // 0..31
#pragma unroll
  for (int i = 0; i < 2; i++) {
    int c = cc + i * 32;
    bf16x8 p;
#pragma unroll
    for (int j = 0; j < 8; j++) p[j] = *(const short*)&tile[rb * 8 + j][c];
    *(bf16x8*)(out + (size_t)(c0 + c) * R + r0 + rb * 8) = p;
  }
}

// ---------------- row layernorm (D=1024), 256 threads/row ----------------
template <bool WF32>
__global__ void k_ln(const float* __restrict__ in, const float* __restrict__ g,
                     const float* __restrict__ b, bf16* __restrict__ ob,
                     float* __restrict__ of) {
  int row = blockIdx.x;
  int tid = threadIdx.x;
  const float4* x4 = (const float4*)(in + (size_t)row * kD);
  float4 v = x4[tid];
  float sum = v.x + v.y + v.z + v.w;
  float sq = fmaf(v.x, v.x, fmaf(v.y, v.y, fmaf(v.z, v.z, v.w * v.w)));
#pragma unroll
  for (int o = 32; o > 0; o >>= 1) {
    sum += __shfl_down(sum, o);
    sq += __shfl_down(sq, o);
  }
  __shared__ float ss[4], sk[4];
  int w = tid >> 6;
  if ((tid & 63) == 0) { ss[w] = sum; sk[w] = sq; }
  __syncthreads();
  float ts = ss[0] + ss[1] + ss[2] + ss[3];
  float tq = sk[0] + sk[1] + sk[2] + sk[3];
  float mu = ts * (1.0f / kD);
  float var = tq * (1.0f / kD) - mu * mu;
  float rstd = rsqrtf(var + 1e-5f);
  float4 gg = ((const float4*)g)[tid];
  float4 bb = ((const float4*)b)[tid];
  float4 o;
  o.x = fmaf((v.x - mu) * rstd, gg.x, bb.x);
  o.y = fmaf((v.y - mu) * rstd, gg.y, bb.y);
  o.z = fmaf((v.z - mu) * rstd, gg.z, bb.z);
  o.w = fmaf((v.w - mu) * rstd, gg.w, bb.w);
  union { ushort4 u; bf16 h[4]; } pk;
  pk.h[0] = __float2bfloat16(o.x);
  pk.h[1] = __float2bfloat16(o.y);
  pk.h[2] = __float2bfloat16(o.z);
  pk.h[3] = __float2bfloat16(o.w);
  *(ushort4*)(ob + (size_t)row * kD + tid * 4) = pk.u;
  if constexpr (WF32) {
    ((float4*)(of + (size_t)row * kD))[tid] = o;
  }
}

// ---------------- phasor scan: pass A (chunk partial sums) ----------------
__global__ void k_scan_part(const float* __restrict__ v, const float* __restrict__ c,
                            const float* __restrict__ s, float* __restrict__ pr,
                            float* __restrict__ pi) {
  int tid = blockIdx.x * 256 + threadIdx.x;  // b*16384 + ch*1024 + d
  int d = tid & (kD - 1);
  int ch = (tid >> 10) & (kNC - 1);
  int b = tid >> 14;
  const float* vp = v + ((size_t)b * kL + ch * kCH) * kD + d;
  const float* cp = c + (size_t)(ch * kCH) * kD + d;
  const float* sp = s + (size_t)(ch * kCH) * kD + d;
  float ar = 0.f, ai = 0.f;
  for (int i = 0; i < kCH; i++) {
    float vv = vp[i * kD];
    ar = fmaf(vv, cp[i * kD], ar);
    ai = fmaf(vv, sp[i * kD], ai);
  }
  pr[tid] = ar;
  pi[tid] = ai;
}

// ---------------- phasor scan: pass B (apply, in-place over v) ----------------
__global__ void k_scan_apply(float* __restrict__ v, const float* __restrict__ c,
                             const float* __restrict__ s, const float* __restrict__ pr,
                             const float* __restrict__ pi) {
  int tid = blockIdx.x * 256 + threadIdx.x;
  int d = tid & (kD - 1);
  int ch = (tid >> 10) & (kNC - 1);
  int b = tid >> 14;
  float ar = 0.f, ai = 0.f;
  int pbase = (b << 14) + d;
  for (int cc = 0; cc < ch; cc++) {
    ar += pr[pbase + cc * kD];
    ai += pi[pbase + cc * kD];
  }
  float* vp = v + ((size_t)b * kL + ch * kCH) * kD + d;
  const float* cp = c + (size_t)(ch * kCH) * kD + d;
  const float* sp = s + (size_t)(ch * kCH) * kD + d;
  for (int i = 0; i < kCH; i++) {
    float vv = vp[i * kD];
    float cv = cp[i * kD], sv = sp[i * kD];
    ar = fmaf(vv, cv, ar);
    ai = fmaf(vv, sv, ai);
    vp[i * kD] = (ar * cv + ai * sv) * 0.03125f;  // 1/sqrt(1024)
  }
}

// ---------------- 128x128-tile GEMM (Round-1 structure) for small D x D ----------------
template <int MODE>
__global__ __launch_bounds__(256) void k_gemm_bt(
    const bf16* __restrict__ A, const bf16* __restrict__ BT,
    const float* __restrict__ bias, const float* __restrict__ xres,
    const float* __restrict__ hres, float* __restrict__ Cout,
    int Md, int Nd, int Kd) {
  __shared__ __align__(16) bf16 As[128 * 32];
  __shared__ __align__(16) bf16 Bs[128 * 32];
  int nwg = gridDim.x * gridDim.y;
  int wg = blockIdx.y * gridDim.x + blockIdx.x;
  int per = nwg >> 3;
  int sw = (wg & 7) * per + (wg >> 3);
  int bm = sw % gridDim.x;
  int bn = sw / gridDim.x;
  int m0 = bm * 128, n0 = bn * 128;
  int tid = threadIdx.x;
  int wid = tid >> 6, lane = tid & 63;
  int wr = wid >> 1, wc = wid & 1;

  f32x4 acc[4][4];
#pragma unroll
  for (int i = 0; i < 4; i++)
#pragma unroll
    for (int j = 0; j < 4; j++) acc[i][j] = (f32x4){0.f, 0.f, 0.f, 0.f};

  const bf16* Abase = A + (size_t)m0 * Kd;
  const bf16* Bbase = BT + (size_t)n0 * Kd;
  int lr = lane >> 2;
  int lk = (lane & 3) * 8;
  int frow = lane & 15;
  int fk = (lane >> 4) * 8;

  for (int k0 = 0; k0 < Kd; k0 += 32) {
#pragma unroll
    for (int c = 0; c < 2; c++) {
      int ch = wid + c * 4;
      __builtin_amdgcn_global_load_lds(GPTR(Abase + (size_t)(ch * 16 + lr) * Kd + k0 + lk),
                                       LPTR(As + ch * 512), 16, 0, 0);
      __builtin_amdgcn_global_load_lds(GPTR(Bbase + (size_t)(ch * 16 + lr) * Kd + k0 + lk),
                                       LPTR(Bs + ch * 512), 16, 0, 0);
    }
    asm volatile("s_waitcnt vmcnt(0)" ::: "memory");
    __syncthreads();
    bf16x8 af[4], bfr[4];
#pragma unroll
    for (int i = 0; i < 4; i++) {
      af[i] = *(const bf16x8*)(As + (wr * 64 + i * 16 + frow) * 32 + fk);
      bfr[i] = *(const bf16x8*)(Bs + (wc * 64 + i * 16 + frow) * 32 + fk);
    }
#pragma unroll
    for (int i = 0; i < 4; i++)
#pragma unroll
      for (int j = 0; j < 4; j++)
        acc[i][j] = __builtin_amdgcn_mfma_f32_16x16x32_bf16(af[i], bfr[j], acc[i][j], 0, 0, 0);
    __syncthreads();
  }

  int cr = (lane >> 4) * 4;
  int ccl = lane & 15;
#pragma unroll
  for (int i = 0; i < 4; i++) {
#pragma unroll
    for (int j = 0; j < 4; j++) {
      int col = n0 + wc * 64 + j * 16 + ccl;
      float bv = bias[col];
#pragma unroll
      for (int r = 0; r < 4; r++) {
        int row = m0 + wr * 64 + i * 16 + cr + r;
        size_t idx = (size_t)row * Nd + col;
        float val = acc[i][j][r] + bv;
        if (MODE == 1) val += hres[idx] + xres[idx];
        Cout[idx] = val;
      }
    }
  }
}

// ============================================================================
// 256x256 8-phase GEMM (R5 body, unchanged schedule), chunked XCD mapping.
// NEW this round: NON-TEMPORAL C stores. The head-GEMM output (1.05 GB f32)
// is never re-read by any kernel; regular stores allocate/evict in L2 and
// churn L3, evicting the B panels (FETCH_SIZE measured 388 MB vs 82 MB
// unique input -> B re-fetched ~5x from HBM, staging-path stalls, MfmaUtil
// 33%). nt stores keep the write stream from displacing A/B in L2/L3.
// Values are bit-identical; only cache policy changes.
// ============================================================================
template <int MODE>
__global__ __launch_bounds__(512, 2) void k_gemm256p8(
    const bf16* __restrict__ A, const bf16* __restrict__ BT,
    const float* __restrict__ bias, const float* __restrict__ xres,
    const float* __restrict__ hres, float* __restrict__ Cout,
    int Md, int Nd, int Kd) {
  __shared__ __align__(16) bf16 As[2][16384];  // [buf][256 rows x 64 k]
  __shared__ __align__(16) bf16 Bs[2][16384];

  int gx = gridDim.x;
  int wg = blockIdx.y * gx + blockIdx.x;
  int mch = gx >> 3;                 // bm-chunk per XCD (gx % 8 == 0)
  int xcd = wg & 7;
  int r = wg >> 3;
  int bm = xcd * mch + (r % mch);
  int bn = r / mch;
  int m0 = bm * 256, n0 = bn * 256;

  int tid = threadIdx.x;
  int wid = tid >> 6, lane = tid & 63;
  int wr = wid >> 2, wc = wid & 3;  // interleaved: A row m*32+wr*16, B row n*64+wc*16

  // ---- staging addressing: thread tid covers (row = tid>>3 within 64-row
  // slab, phys k16 = tid&7); source k16 = (tid&7) ^ (row&7). LDS write is
  // linear (wave-uniform base + lane*16).
  size_t KdS = (size_t)Kd;
  int srow = tid >> 3;                               // 0..63 slab row
  int sk = (((tid & 7) ^ (srow & 7)) << 3);          // source elem offset
  const bf16* aSrc = A + (size_t)(m0 + srow) * KdS + sk;
  const bf16* bSrc = BT + (size_t)(n0 + srow) * KdS + sk;
  int ldst = wid * 512;                              // wave-uniform elem base

#define STAGE_A(buf, h, t)                                                              \
  do {                                                                                  \
    __builtin_amdgcn_global_load_lds(GPTR(aSrc + (size_t)((h) * 128) * KdS + (t) * 64), \
                                     LPTR(&As[buf][(h) * 8192 + ldst]), 16, 0, 0);      \
    __builtin_amdgcn_global_load_lds(                                                   \
        GPTR(aSrc + (size_t)((h) * 128 + 64) * KdS + (t) * 64),                         \
        LPTR(&As[buf][(h) * 8192 + 4096 + ldst]), 16, 0, 0);                            \
  } while (0)
#define STAGE_B(buf, h, t)                                                              \
  do {                                                                                  \
    __builtin_amdgcn_global_load_lds(GPTR(bSrc + (size_t)((h) * 128) * KdS + (t) * 64), \
                                     LPTR(&Bs[buf][(h) * 8192 + ldst]), 16, 0, 0);      \
    __builtin_amdgcn_global_load_lds(                                                   \
        GPTR(bSrc + (size_t)((h) * 128 + 64) * KdS + (t) * 64),                         \
        LPTR(&Bs[buf][(h) * 8192 + 4096 + ldst]), 16, 0, 0);                            \
  } while (0)

  // ---- fragment read offsets (elem units; row stride 64) ----
  int frow = lane & 15;
  int khi = lane >> 4;   // 0..3
  int rx = frow & 7;
  int lk0 = ((khi) ^ rx) << 3;        // k-window 0 (k 0..31)
  int lk1 = ((4 + khi) ^ rx) << 3;    // k-window 1 (k 32..63)
  int wr16 = wr * 16, wc16 = wc * 16;

  f32x4 acc[8][4];
#pragma unroll
  for (int m = 0; m < 8; m++)
#pragma unroll
    for (int n = 0; n < 4; n++) acc[m][n] = (f32x4){0.f, 0.f, 0.f, 0.f};

  const int NT = Kd >> 6;  // 16 K-tiles of 64

  // ---- prologue: tile0 fully -> buf0 (A0,B0,B1,A1), tile1 A0,B0,B1 -> buf1
  STAGE_A(0, 0, 0);
  STAGE_B(0, 0, 0);
  STAGE_B(0, 1, 0);
  STAGE_A(0, 1, 0);
  STAGE_A(1, 0, 1);
  STAGE_B(1, 0, 1);
  STAGE_B(1, 1, 1);
  asm volatile("s_waitcnt vmcnt(6)" ::: "memory");  // tile0's 8 loads landed
  __builtin_amdgcn_s_barrier();
  __builtin_amdgcn_sched_barrier(0);

  for (int t = 0; t < NT; ++t) {
    int c = t & 1, o = c ^ 1;
    const bf16* Ac = As[c];
    const bf16* Bc = Bs[c];
    bf16x8 a[4][2], b[2][2], b2[2][2];

    // ===== phase 0: read a(m0..3) + b(n0..1); stage A-h1(t+1)->oth;
    //       MFMA (m0..3 x n0..1)
#pragma unroll
    for (int m = 0; m < 4; m++) {
      int ro = (m * 32 + wr16 + frow) * 64;
      a[m][0] = *(const bf16x8*)(Ac + ro + lk0);
      a[m][1] = *(const bf16x8*)(Ac + ro + lk1);
    }
#pragma unroll
    for (int n = 0; n < 2; n++) {
      int ro = (n * 64 + wc16 + frow) * 64;
      b[n][0] = *(const bf16x8*)(Bc + ro + lk0);
      b[n][1] = *(const bf16x8*)(Bc + ro + lk1);
    }
    if (t + 1 < NT) STAGE_A(o, 1, t + 1);
    __builtin_amdgcn_s_barrier();
    asm volatile("s_waitcnt lgkmcnt(0)" ::: "memory");
    __builtin_amdgcn_sched_barrier(0);
    __builtin_amdgcn_s_setprio(1);
#pragma unroll
    for (int m = 0; m < 4; m++)
#pragma unroll
      for (int n = 0; n < 2; n++) {
        acc[m][n] = __builtin_amdgcn_mfma_f32_16x16x32_bf16(a[m][0], b[n][0], acc[m][n], 0, 0, 0);
        acc[m][n] = __builtin_amdgcn_mfma_f32_16x16x32_bf16(a[m][1], b[n][1], acc[m][n], 0, 0, 0);
      }
    __builtin_amdgcn_s_setprio(0);
    __builtin_amdgcn_s_barrier();
    __builtin_amdgcn_sched_barrier(0);

    // ===== phase 1: read b2(n2..3); stage A-h0(t+2)->cur; MFMA (m0..3 x n2..3)
#pragma unroll
    for (int n = 0; n < 2; n++) {
      int ro = ((n + 2) * 64 + wc16 + frow) * 64;
      b2[n][0] = *(const bf16x8*)(Bc + ro + lk0);
      b2[n][1] = *(const bf16x8*)(Bc + ro + lk1);
    }
    if (t + 2 < NT) STAGE_A(c, 0, t + 2);
    __builtin_amdgcn_s_barrier();
    asm volatile("s_waitcnt lgkmcnt(0)" ::: "memory");
    __builtin_amdgcn_sched_barrier(0);
    __builtin_amdgcn_s_setprio(1);
#pragma unroll
    for (int m = 0; m < 4; m++)
#pragma unroll
      for (int n = 0; n < 2; n++) {
        acc[m][n + 2] = __builtin_amdgcn_mfma_f32_16x16x32_bf16(a[m][0], b2[n][0], acc[m][n + 2], 0, 0, 0);
        acc[m][n + 2] = __builtin_amdgcn_mfma_f32_16x16x32_bf16(a[m][1], b2[n][1], acc[m][n + 2], 0, 0, 0);
      }
    __builtin_amdgcn_s_setprio(0);
    __builtin_amdgcn_s_barrier();
    __builtin_amdgcn_sched_barrier(0);

    // ===== phase 2: read a(m4..7); stage B-h0(t+2)->cur; MFMA (m4..7 x n0..1)
#pragma unroll
    for (int m = 0; m < 4; m++) {
      int ro = ((m + 4) * 32 + wr16 + frow) * 64;
      a[m][0] = *(const bf16x8*)(Ac + ro + lk0);
      a[m][1] = *(const bf16x8*)(Ac + ro + lk1);
    }
    if (t + 2 < NT) STAGE_B(c, 0, t + 2);
    __builtin_amdgcn_s_barrier();
    asm volatile("s_waitcnt lgkmcnt(0)" ::: "memory");
    __builtin_amdgcn_sched_barrier(0);
    __builtin_amdgcn_s_setprio(1);
#pragma unroll
    for (int m = 0; m < 4; m++)
#pragma unroll
      for (int n = 0; n < 2; n++) {
        acc[m + 4][n] = __builtin_amdgcn_mfma_f32_16x16x32_bf16(a[m][0], b[n][0], acc[m + 4][n], 0, 0, 0);
        acc[m + 4][n] = __builtin_amdgcn_mfma_f32_16x16x32_bf16(a[m][1], b[n][1], acc[m + 4][n], 0, 0, 0);
      }
    __builtin_amdgcn_s_setprio(0);
    __builtin_amdgcn_s_barrier();
    __builtin_amdgcn_sched_barrier(0);

    // ===== phase 3: no reads; stage B-h1(t+2)->cur; MFMA (m4..7 x n2..3); gate
    if (t + 2 < NT) STAGE_B(c, 1, t + 2);
    __builtin_amdgcn_s_barrier();
    __builtin_amdgcn_sched_barrier(0);
    __builtin_amdgcn_s_setprio(1);
#pragma unroll
    for (int m = 0; m < 4; m++)
#pragma unroll
      for (int n = 0; n < 2; n++) {
        acc[m + 4][n + 2] = __builtin_amdgcn_mfma_f32_16x16x32_bf16(a[m][0], b2[n][0], acc[m + 4][n + 2], 0, 0, 0);
        acc[m + 4][n + 2] = __builtin_amdgcn_mfma_f32_16x16x32_bf16(a[m][1], b2[n][1], acc[m + 4][n + 2], 0, 0, 0);
      }
    __builtin_amdgcn_s_setprio(0);
    if (t < NT - 2) {
      asm volatile("s_waitcnt vmcnt(6)" ::: "memory");  // 3 half-tiles in flight
    } else if (t == NT - 2) {
      asm volatile("s_waitcnt vmcnt(0)" ::: "memory");  // drain for last tile
    }
    __builtin_amdgcn_s_barrier();
    __builtin_amdgcn_sched_barrier(0);
  }
#undef STAGE_A
#undef STAGE_B

  // ---- epilogue (interleaved mapping); nt stores: output is never re-read ----
  int cr = (lane >> 4) * 4;
  int ccl = lane & 15;
#pragma unroll
  for (int m = 0; m < 8; m++) {
#pragma unroll
    for (int n = 0; n < 4; n++) {
      int col = n0 + n * 64 + wc16 + ccl;
      float bvv = bias[col];
#pragma unroll
      for (int r2 = 0; r2 < 4; r2++) {
        int row = m0 + m * 32 + wr16 + cr + r2;
        size_t idx = (size_t)row * Nd + col;
        float val = acc[m][n][r2] + bvv;
        if (MODE == 1) val += hres[idx] + xres[idx];
        __builtin_nontemporal_store(val, &Cout[idx]);
      }
    }
  }
}

extern "C" void kernel_launch(void* const* d_in, const int* in_sizes, int n_in,
                              void* d_out, int out_size, void* d_ws, size_t ws_size,
                              hipStream_t stream) {
  const int* tokens   = (const int*)d_in[0];
  const float* embed  = (const float*)d_in[1];
  const float* ln1_g  = (const float*)d_in[2];
  const float* ln1_b  = (const float*)d_in[3];
  const float* ph1    = (const float*)d_in[4];
  const float* wv1    = (const float*)d_in[5];
  const float* bv1    = (const float*)d_in[6];
  const float* lno1_g = (const float*)d_in[7];
  const float* lno1_b = (const float*)d_in[8];
  const float* wo1    = (const float*)d_in[9];
  const float* bo1    = (const float*)d_in[10];
  const float* ln2_g  = (const float*)d_in[11];
  const float* ln2_b  = (const float*)d_in[12];
  const float* ph2    = (const float*)d_in[13];
  const float* wv2    = (const float*)d_in[14];
  const float* bv2    = (const float*)d_in[15];
  const float* lno2_g = (const float*)d_in[16];
  const float* lno2_b = (const float*)d_in[17];
  const float* wo2    = (const float*)d_in[18];
  const float* bo2    = (const float*)d_in[19];
  const float* ln3_g  = (const float*)d_in[20];
  const float* ln3_b  = (const float*)d_in[21];
  const float* w_head = (const float*)d_in[22];
  const float* b_head = (const float*)d_in[23];

  float* out = (float*)d_out;

  // ws: bf16 weights (transposed) + bf16 LN output  (~91 MB)
  char* ws = (char*)d_ws;
  bf16* whT  = (bf16*)ws;                    // [V][D]
  bf16* wv1T = whT + (size_t)kV * kD;        // [D][D] each
  bf16* wo1T = wv1T + (size_t)kD * kD;
  bf16* wv2T = wo1T + (size_t)kD * kD;
  bf16* wo2T = wv2T + (size_t)kD * kD;
  bf16* xb   = wo2T + (size_t)kD * kD;       // [M][D] bf16 (LN output, reused)

  // f32 activations live in d_out (1 GB); fully overwritten by the final GEMM
  float* h  = out;                            // [M][D]
  float* xf = h + (size_t)kM * kD;            // [M][D]
  float* vb = xf + (size_t)kM * kD;           // [M][D] v / retrieved (in-place)
  float* ct = vb + (size_t)kM * kD;           // [L][D]
  float* st = ct + (size_t)kL * kD;           // [L][D]
  float* pr = st + (size_t)kL * kD;           // [B][NC][D]
  float* pi = pr + (size_t)kB * kNC * kD;

  // weight conversion (transpose to [N][K] bf16), 64x64 vectorized tiles
  k_tcvt64<<<dim3(kD / 64, kD / 64), 256, 0, stream>>>(wv1, wv1T, kD, kD);
  k_tcvt64<<<dim3(kD / 64, kD / 64), 256, 0, stream>>>(wo1, wo1T, kD, kD);
  k_tcvt64<<<dim3(kD / 64, kD / 64), 256, 0, stream>>>(wv2, wv2T, kD, kD);
  k_tcvt64<<<dim3(kD / 64, kD / 64), 256, 0, stream>>>(wo2, wo2T, kD, kD);
  k_tcvt64<<<dim3(kV / 64, kD / 64), 256, 0, stream>>>(w_head, whT, kD, kV);

  k_embed<<<kM, 256, 0, stream>>>(tokens, embed, h);

  const int scanBlocks = kB * kNC * kD / 256;  // 256

  // ---- phasor block 1 ----
  k_sincos<<<(kL * kD + 255) / 256, 256, 0, stream>>>(ph1, ct, st, kL * kD);
  k_ln<true><<<kM, 256, 0, stream>>>(h, ln1_g, ln1_b, xb, xf);
  k_gemm_bt<0><<<dim3(kM / 128, kD / 128), 256, 0, stream>>>(xb, wv1T, bv1, nullptr, nullptr,
                                                             vb, kM, kD, kD);
  k_scan_part<<<scanBlocks, 256, 0, stream>>>(vb, ct, st, pr, pi);
  k_scan_apply<<<scanBlocks, 256, 0, stream>>>(vb, ct, st, pr, pi);
  k_ln<false><<<kM, 256, 0, stream>>>(vb, lno1_g, lno1_b, xb, nullptr);
  k_gemm_bt<1><<<dim3(kM / 128, kD / 128), 256, 0, stream>>>(xb, wo1T, bo1, xf, h,
                                                             h, kM, kD, kD);

  // ---- phasor block 2 ----
  k_sincos<<<(kL * kD + 255) / 256, 256, 0, stream>>>(ph2, ct, st, kL * kD);
  k_ln<true><<<kM, 256, 0, stream>>>(h, ln2_g, ln2_b, xb, xf);
  k_gemm_bt<0><<<dim3(kM / 128, kD / 128), 256, 0, stream>>>(xb, wv2T, bv2, nullptr, nullptr,
                                                             vb, kM, kD, kD);
  k_scan_part<<<scanBlocks, 256, 0, stream>>>(vb, ct, st, pr, pi);
  k_scan_apply<<<scanBlocks, 256, 0, stream>>>(vb, ct, st, pr, pi);
  k_ln<false><<<kM, 256, 0, stream>>>(vb, lno2_g, lno2_b, xb, nullptr);
  k_gemm_bt<1><<<dim3(kM / 128, kD / 128), 256, 0, stream>>>(xb, wo2T, bo2, xf, h,
                                                             h, kM, kD, kD);

  // ---- final LN + head GEMM (256^2, 4-phase/K-tile, chunked-XCD, nt C-stores) ----
  k_ln<false><<<kM, 256, 0, stream>>>(h, ln3_g, ln3_b, xb, nullptr);
  k_gemm256p8<0><<<dim3(kM / 256, kV / 256), 512, 0, stream>>>(xb, whT, b_head, nullptr,
                                                               nullptr, out, kM, kV, kD);
}